// Round 1
// baseline (125.028 us; speedup 1.0000x reference)
//
#include <hip/hip_runtime.h>
#include <math.h>

#define J 5

// Fast hardware reciprocal / rsqrt (v_rcp_f32 / v_rsq_f32, ~1e-5 rel err —
// far below the test threshold). Guarded so the host pass still compiles.
#if defined(__HIP_DEVICE_COMPILE__) && __has_builtin(__builtin_amdgcn_rcpf)
__device__ __forceinline__ float fastrcp(float x) { return __builtin_amdgcn_rcpf(x); }
#else
__device__ __forceinline__ float fastrcp(float x) { return 1.0f / x; }
#endif

#if defined(__HIP_DEVICE_COMPILE__) && __has_builtin(__builtin_amdgcn_rsqf)
__device__ __forceinline__ float fastrsq(float x) { return __builtin_amdgcn_rsqf(x); }
#else
__device__ __forceinline__ float fastrsq(float x) { return 1.0f / sqrtf(x); }
#endif

// tanh(y) = 1 - 2/(e^{2y}+1): saturates cleanly at +-1, no inf/inf NaN.
__device__ __forceinline__ float fast_tanh_from_e2y(float e2y) {
    return fmaf(-2.0f, fastrcp(e2y + 1.0f), 1.0f);
}

__global__ __launch_bounds__(256) void smile_kernel(
    const float* __restrict__ ttm,     const float* __restrict__ logm,
    const float* __restrict__ w_logm,  const float* __restrict__ b_logm,
    const float* __restrict__ w_ttm,   const float* __restrict__ b_ttm,
    const float* __restrict__ w_exp,   const float* __restrict__ b_exp,
    const float* __restrict__ W1,      const float* __restrict__ b1,
    const float* __restrict__ W2,      const float* __restrict__ b2,
    const float* __restrict__ Wo,      const float* __restrict__ bo,
    float* __restrict__ out, int n)
{
    const int tid = blockIdx.x * blockDim.x + threadIdx.x;
    const int i0  = tid * 4;
    if (i0 >= n) return;

    // ---- per-thread parameter prep (amortized over 4 samples) ----
    float ewl[J], bl[J], ewt[J], bt[J], ewe[J], wte[J];
#pragma unroll
    for (int j = 0; j < J; ++j) {
        ewl[j] = __expf(w_logm[j]);
        bl[j]  = b_logm[j];
        ewt[j] = __expf(w_ttm[j]);
        bt[j]  = b_ttm[j];
        ewe[j] = __expf(w_exp[j]);
        wte[j] = ewt[j] * ewe[j];
    }
    // Layer-1 folds: h0_j = s + be_j (s uniform over j), so
    // a_i = s*r1_i + c1_i with r1_i = sum_j W1[i,j], c1_i = b1_i + sum_j W1[i,j]*be_j
    float r1[J], c1[J];
#pragma unroll
    for (int i = 0; i < J; ++i) {
        float r = 0.0f, c = b1[i];
#pragma unroll
        for (int j = 0; j < J; ++j) {
            const float w = W1[i * J + j];
            r += w;
            c = fmaf(w, b_exp[j], c);
        }
        r1[i] = r; c1[i] = c;
    }
    const float bo0 = bo[0];

    // ---- load 4 samples ----
    const float4 T4 = ((const float4*)ttm)[tid];
    const float4 L4 = ((const float4*)logm)[tid];
    float Ts[4] = {T4.x, T4.y, T4.z, T4.w};
    float Ls[4] = {L4.x, L4.y, L4.z, L4.w};
    float O0[4], O1[4], O2[4], O3[4];

#pragma unroll
    for (int k = 0; k < 4; ++k) {
        const float L = Ls[k], T = Ts[k];

        // ---- smile term + sigmoid term, with d/dlogm, d2/dlogm2, d/dttm ----
        float s = 0.0f, sL = 0.0f, sLL = 0.0f, sT = 0.0f;
#pragma unroll
        for (int j = 0; j < J; ++j) {
            const float x  = fmaf(L, ewl[j], bl[j]);
            const float t1 = fast_tanh_from_e2y(__expf(fmaf(2.0f, x, 1.0f))); // tanh(x+0.5)
            const float t2 = fast_tanh_from_e2y(__expf(-x));                  // tanh(-x/2)
            const float m1 = fmaf(-t1, t1, 1.0f);   // sech^2(x+0.5)
            const float m2 = fmaf(-t2, t2, 1.0f);   // sech^2(x/2)
            const float u  = fmaf(x, t1, t2) + 5.0e-4f;
            const float xm1 = x * m1;
            const float ux  = fmaf(-0.5f, m2, t1 + xm1);
            // uxx = 2*(m1 - t1*x*m1) - 0.5*t2*m2
            const float uxx = fmaf(-0.5f * t2, m2, 2.0f * fmaf(-t1, xm1, m1));
            const float r   = fastrsq(u);       // 1/sqrt(u)
            const float tl  = u * r;            // sqrt(u)
            const float i2  = 0.5f * r;         // 1/(2 sqrt(u))
            const float ru  = r * r;            // 1/u
            const float tlL  = ux * ewl[j] * i2;
            const float tlLL = (ewl[j] * ewl[j]) * i2 * fmaf(-0.5f * ux, ux * ru, uxx);
            // tt = sigmoid(bt + T*ewt)
            const float z   = fmaf(T, ewt[j], bt[j]);
            const float tt  = fastrcp(1.0f + __expf(-z));
            const float dtt = fmaf(-tt, tt, tt);     // tt*(1-tt)
            const float A   = tt * ewe[j];
            s   = fmaf(tl,   A, s);
            sL  = fmaf(tlL,  A, sL);
            sLL = fmaf(tlLL, A, sLL);
            sT  = fmaf(tl * dtt, wte[j], sT);
        }

        // ---- layer 1 (folded affine) + softplus ----
        float h1[J], h1L[J], h1LL[J], h1T[J];
#pragma unroll
        for (int i = 0; i < J; ++i) {
            const float a   = fmaf(s, r1[i], c1[i]);
            const float aL  = sL  * r1[i];
            const float aLL = sLL * r1[i];
            const float aT  = sT  * r1[i];
            const float sg  = fastrcp(1.0f + __expf(-a));
            const float sp  = a - __logf(sg);        // softplus(a) = a - ln(sigmoid(a))
            const float dsg = fmaf(-sg, sg, sg);     // sg*(1-sg)
            h1[i]   = sp;
            h1L[i]  = sg * aL;
            h1LL[i] = fmaf(dsg * aL, aL, sg * aLL);
            h1T[i]  = sg * aT;
        }

        // ---- layer 2 + softplus + output head ----
        float o = bo0, oL = 0.0f, oLL = 0.0f, oT = 0.0f;
#pragma unroll
        for (int i = 0; i < J; ++i) {
            float g = b2[i], gL = 0.0f, gLL = 0.0f, gT = 0.0f;
#pragma unroll
            for (int j = 0; j < J; ++j) {
                const float w = W2[i * J + j];
                g   = fmaf(w, h1[j],   g);
                gL  = fmaf(w, h1L[j],  gL);
                gLL = fmaf(w, h1LL[j], gLL);
                gT  = fmaf(w, h1T[j],  gT);
            }
            const float sg  = fastrcp(1.0f + __expf(-g));
            const float sp  = g - __logf(sg);
            const float dsg = fmaf(-sg, sg, sg);
            const float wo  = Wo[i];
            o   = fmaf(wo, sp, o);
            oL  = fmaf(wo, sg * gL, oL);
            oLL = fmaf(wo, fmaf(dsg * gL, gL, sg * gLL), oLL);
            oT  = fmaf(wo, sg * gT, oT);
        }

        O0[k] = o;   // output
        O1[k] = oT;  // grad_ttm1
        O2[k] = oL;  // grad_logm1
        O3[k] = oLL; // grad_logm2
    }

    // ---- coalesced float4 stores into the 4 concatenated output segments ----
    ((float4*)(out))[tid]                       = make_float4(O0[0], O0[1], O0[2], O0[3]);
    ((float4*)(out + (size_t)n))[tid]           = make_float4(O1[0], O1[1], O1[2], O1[3]);
    ((float4*)(out + 2 * (size_t)n))[tid]       = make_float4(O2[0], O2[1], O2[2], O2[3]);
    ((float4*)(out + 3 * (size_t)n))[tid]       = make_float4(O3[0], O3[1], O3[2], O3[3]);
}

extern "C" void kernel_launch(void* const* d_in, const int* in_sizes, int n_in,
                              void* d_out, int out_size, void* d_ws, size_t ws_size,
                              hipStream_t stream) {
    const float* ttm    = (const float*)d_in[0];
    const float* logm   = (const float*)d_in[1];
    const float* w_logm = (const float*)d_in[2];
    const float* b_logm = (const float*)d_in[3];
    const float* w_ttm  = (const float*)d_in[4];
    const float* b_ttm  = (const float*)d_in[5];
    const float* w_exp  = (const float*)d_in[6];
    const float* b_exp  = (const float*)d_in[7];
    const float* W1     = (const float*)d_in[8];
    const float* b1     = (const float*)d_in[9];
    const float* W2     = (const float*)d_in[10];
    const float* b2     = (const float*)d_in[11];
    const float* Wo     = (const float*)d_in[12];
    const float* bo     = (const float*)d_in[13];
    float* out = (float*)d_out;

    const int n = in_sizes[0];
    const int threads = (n + 3) / 4;
    const int blocks  = (threads + 255) / 256;
    smile_kernel<<<blocks, 256, 0, stream>>>(
        ttm, logm, w_logm, b_logm, w_ttm, b_ttm, w_exp, b_exp,
        W1, b1, W2, b2, Wo, bo, out, n);
}